// Round 1
// baseline (1374.509 us; speedup 1.0000x reference)
//
#include <hip/hip_runtime.h>

// EPN_flax: N=1024 atoms, T=3 timesteps.
// Per t: antisym[i,j] = (MLP([a_i,a_j,e_ij]) - MLP([a_j,a_i,e_ij])) * mask[i,j]
//        q += sum_j antisym
// Algebra: layer1 = P[i] + Q[j] + E[i,j] (+b0), with P=a@W0[0:32], Q=a@W0[32:64],
// E=e@W0[64:80] shared between both directions; b2 cancels in the antisymmetry.

constexpr int Nn = 1024;

__global__ __launch_bounds__(256, 1)
void epn_pair_kernel(const float* __restrict__ h,
                     const float* __restrict__ qread,
                     const float* __restrict__ e,
                     const float* __restrict__ mask,
                     const float* __restrict__ W0t,   // [80][64]
                     const float* __restrict__ b0t,   // [64]
                     const float* __restrict__ W1t,   // [64][64]
                     const float* __restrict__ b1t,   // [64]
                     const float* __restrict__ W2t,   // [64]
                     float* __restrict__ qout)
{
    __shared__ float  sa[32][32];      // a-rows: 16 i-rows then 16 j-rows
    __shared__ float2 sAi[16][64];     // (P,Q) for i-rows
    __shared__ float2 sAj[16][64];     // (P,Q) for j-rows
    __shared__ float  sW1[64][64];
    __shared__ float  sW0eT[64][16];   // transposed e-slice of W0: [k][c]
    __shared__ float  sb0[64];
    __shared__ float  sb1[64];
    __shared__ float  sW2[64];

    const int tid = threadIdx.x;
    const int i0 = blockIdx.y * 16;
    const int j0 = blockIdx.x * 16;

    // ---- stage a = [h, q] for the 32 atoms this block touches ----
    for (int idx = tid; idx < 32 * 32; idx += 256) {
        int r = idx >> 5, c = idx & 31;
        int atom = (r < 16) ? (i0 + r) : (j0 + (r - 16));
        sa[r][c] = (c < 31) ? h[atom * 31 + c] : qread[atom];
    }
    // ---- stage weights ----
    for (int idx = tid; idx < 64 * 64; idx += 256)
        sW1[idx >> 6][idx & 63] = W1t[idx];
    for (int idx = tid; idx < 16 * 64; idx += 256) {
        int c = idx >> 6, k = idx & 63;
        sW0eT[k][c] = W0t[(64 + c) * 64 + k];
    }
    if (tid < 64) {
        sb0[tid] = b0t[tid];
        sb1[tid] = b1t[tid];
        sW2[tid] = W2t[tid];
    }
    __syncthreads();

    // ---- per-atom projections P,Q for the 32 staged rows ----
    {
        int k  = tid & 63;     // output column
        int rg = tid >> 6;     // row group 0..3 (8 rows each)
        float accP[8], accQ[8];
        #pragma unroll
        for (int m = 0; m < 8; ++m) { accP[m] = 0.f; accQ[m] = 0.f; }
        for (int c = 0; c < 32; ++c) {
            float w0a = W0t[c * 64 + k];          // coalesced, L1-resident
            float w0b = W0t[(32 + c) * 64 + k];
            #pragma unroll
            for (int m = 0; m < 8; ++m) {
                float av = sa[rg * 8 + m][c];     // LDS broadcast (wave-uniform)
                accP[m] = fmaf(av, w0a, accP[m]);
                accQ[m] = fmaf(av, w0b, accQ[m]);
            }
        }
        #pragma unroll
        for (int m = 0; m < 8; ++m) {
            int r = rg * 8 + m;
            if (r < 16) sAi[r][k]      = make_float2(accP[m], accQ[m]);
            else        sAj[r - 16][k] = make_float2(accP[m], accQ[m]);
        }
    }
    __syncthreads();

    // ---- main per-pair MLP ----
    const int tj = tid & 15, ti = tid >> 4;
    const size_t pairIdx = (size_t)(i0 + ti) * Nn + (size_t)(j0 + tj);
    const float4* e4 = (const float4*)(e + pairIdx * 16);
    float4 ea = e4[0], eb = e4[1], ec = e4[2], ed = e4[3];
    float ev[16] = {ea.x, ea.y, ea.z, ea.w, eb.x, eb.y, eb.z, eb.w,
                    ec.x, ec.y, ec.z, ec.w, ed.x, ed.y, ed.z, ed.w};
    const float mval = mask[pairIdx];

    float h2u[64], h2v[64];
    #pragma unroll
    for (int x = 0; x < 64; ++x) { h2u[x] = sb1[x]; h2v[x] = sb1[x]; }

    #pragma unroll 2
    for (int k = 0; k < 64; ++k) {
        // E_k = b0[k] + e . W0e[:,k]
        float ek = sb0[k];
        #pragma unroll
        for (int c = 0; c < 16; c += 4) {
            float4 w = *(const float4*)&sW0eT[k][c];   // broadcast b128
            ek = fmaf(ev[c + 0], w.x, ek);
            ek = fmaf(ev[c + 1], w.y, ek);
            ek = fmaf(ev[c + 2], w.z, ek);
            ek = fmaf(ev[c + 3], w.w, ek);
        }
        float2 ai = sAi[ti][k];   // (P[i], Q[i])
        float2 aj = sAj[tj][k];   // (P[j], Q[j])
        float u = fmaxf(ek + ai.x + aj.y, 0.f);   // dir ij: P[i]+Q[j]+E
        float v = fmaxf(ek + aj.x + ai.y, 0.f);   // dir ji: P[j]+Q[i]+E
        #pragma unroll
        for (int k2 = 0; k2 < 64; k2 += 4) {
            float4 w = *(const float4*)&sW1[k][k2];    // broadcast b128, shared u/v
            h2u[k2 + 0] = fmaf(u, w.x, h2u[k2 + 0]);
            h2u[k2 + 1] = fmaf(u, w.y, h2u[k2 + 1]);
            h2u[k2 + 2] = fmaf(u, w.z, h2u[k2 + 2]);
            h2u[k2 + 3] = fmaf(u, w.w, h2u[k2 + 3]);
            h2v[k2 + 0] = fmaf(v, w.x, h2v[k2 + 0]);
            h2v[k2 + 1] = fmaf(v, w.y, h2v[k2 + 1]);
            h2v[k2 + 2] = fmaf(v, w.z, h2v[k2 + 2]);
            h2v[k2 + 3] = fmaf(v, w.w, h2v[k2 + 3]);
        }
    }

    // layer 3: s = (relu(h2u) - relu(h2v)) . W2   (b2 cancels)
    float s = 0.f;
    #pragma unroll
    for (int k2 = 0; k2 < 64; ++k2)
        s += (fmaxf(h2u[k2], 0.f) - fmaxf(h2v[k2], 0.f)) * sW2[k2];
    s *= mval;

    // reduce over the 16 j-lanes of this row
    s += __shfl_down(s, 8, 16);
    s += __shfl_down(s, 4, 16);
    s += __shfl_down(s, 2, 16);
    s += __shfl_down(s, 1, 16);
    if (tj == 0) atomicAdd(&qout[i0 + ti], s);
}

extern "C" void kernel_launch(void* const* d_in, const int* in_sizes, int n_in,
                              void* d_out, int out_size, void* d_ws, size_t ws_size,
                              hipStream_t stream) {
    const float* h    = (const float*)d_in[0];
    const float* e    = (const float*)d_in[1];
    const float* q    = (const float*)d_in[2];
    const float* mask = (const float*)d_in[3];
    // d_in[4] = natom (int, ==1024), hard-coded
    const float* W0   = (const float*)d_in[5];
    const float* b0   = (const float*)d_in[6];
    const float* W1   = (const float*)d_in[7];
    const float* b1   = (const float*)d_in[8];
    const float* W2   = (const float*)d_in[9];
    // d_in[10] = b2: cancels in the antisymmetrization

    float* qout = (float*)d_out;       // running q, accumulated in place
    float* qA   = (float*)d_ws;        // stable read copy per timestep (4 KB)

    hipMemcpyAsync(qout, q, Nn * sizeof(float), hipMemcpyDeviceToDevice, stream);
    for (int t = 0; t < 3; ++t) {
        // snapshot current q so the kernel reads a stable copy while atomically
        // accumulating deltas into qout
        hipMemcpyAsync(qA, qout, Nn * sizeof(float), hipMemcpyDeviceToDevice, stream);
        epn_pair_kernel<<<dim3(64, 64), 256, 0, stream>>>(
            h, qA, e, mask,
            W0 + t * 80 * 64, b0 + t * 64,
            W1 + t * 64 * 64, b1 + t * 64,
            W2 + t * 64, qout);
    }
}

// Round 3
// 962.425 us; speedup vs baseline: 1.4282x; 1.4282x over previous
//
#include <hip/hip_runtime.h>

// EPN_flax, MFMA, transposed orientation: D1[hidden, pair] = W0''^T @ X so the
// layer-1 accumulators ARE the layer-2 B-operand (zero-shuffle handoff).
// Precision: q fed as bf16 hi+lo features with hi+lo weight rows (kg 81-84);
// layer-1 activations hi/lo-split and layer 2 run over K'=128 interleaved:
//   h2 = (W1hi)·uhi + (W1hi)·ulo   [A=(W1hi,W1hi) dup, B=(uhi,ulo)]
//      + (W1lo)·uhi                [A=(W1lo,0),      B=(uhi,ulo)]
// b2 cancels in the antisymmetrization; b0 folded as a constant-1 feature.

constexpr int Nn = 1024;

typedef __attribute__((ext_vector_type(8))) short short8;
typedef __attribute__((ext_vector_type(4))) float f32x4;

#define MFMA16(A, B, C) __builtin_amdgcn_mfma_f32_16x16x32_bf16(A, B, C, 0, 0, 0)

__device__ inline unsigned int rne(float x) {            // round-to-nearest-even bits
    unsigned int u = __float_as_uint(x);
    return u + 0x7FFFu + ((u >> 16) & 1u);
}
__device__ inline unsigned short f2bf(float x) { return (unsigned short)(rne(x) >> 16); }
__device__ inline float bf2f(unsigned short h) { return __uint_as_float(((unsigned int)h) << 16); }

union U8 { unsigned int u[4]; short8 s; };

__global__ __launch_bounds__(256)
void epn_mfma_kernel(const float* __restrict__ h,
                     const float* __restrict__ qread,
                     const float* __restrict__ e,
                     const float* __restrict__ mask,
                     const float* __restrict__ W0t,   // [80][64]
                     const float* __restrict__ b0t,   // [64]
                     const float* __restrict__ W1t,   // [64][64]
                     const float* __restrict__ b1t,   // [64]
                     const float* __restrict__ W2t,   // [64]
                     float* __restrict__ qout)
{
    __shared__ __align__(16) unsigned short sa[32][40];     // bf16 a=[h,qhi]; 0-15 i, 16-31 j
    __shared__ unsigned short sqres[32];                    // bf16 q lo-residual
    __shared__ __align__(16) unsigned short se[16][16][24]; // bf16 e tile [il][j][c]
    __shared__ float smask[16][16];
    __shared__ __align__(16) unsigned short sW1loD[4][4][4][16][8]; // [s'][t2][qd][nl][j]: (W1lo,0)
    __shared__ __align__(16) float sb1f[64];
    __shared__ __align__(16) float sw2f[64];

    const int tid  = threadIdx.x;
    const int lane = tid & 63;
    const int wv   = tid >> 6;
    const int nl   = lane & 15;
    const int qd   = lane >> 4;
    const int i0   = blockIdx.y * 16;
    const int j0   = blockIdx.x * 16;

    // ---------------- staging ----------------
    for (int idx = tid; idx < 32 * 32; idx += 256) {
        int r = idx >> 5, c = idx & 31;
        int atom = (r < 16) ? (i0 + r) : (j0 + (r - 16));
        if (c < 31) {
            sa[r][c] = f2bf(h[atom * 31 + c]);
        } else {
            float qv = qread[atom];
            unsigned short hi = f2bf(qv);
            sa[r][31] = hi;
            sqres[r] = f2bf(qv - bf2f(hi));
        }
    }
    for (int rep = 0; rep < 4; ++rep) {
        int lin = rep * 256 + tid;          // 0..1023 float4s of the e tile
        int il = lin >> 6, f4 = lin & 63;
        const float4* src = (const float4*)(e + (size_t)(i0 + il) * Nn * 16 + (size_t)j0 * 16);
        float4 v = src[f4];
        int j = f4 >> 2, c4 = (f4 & 3) * 4;
        unsigned short* dst = &se[il][j][c4];
        dst[0] = f2bf(v.x); dst[1] = f2bf(v.y); dst[2] = f2bf(v.z); dst[3] = f2bf(v.w);
    }
    {
        int il = tid >> 4, j = tid & 15;
        smask[il][j] = mask[(size_t)(i0 + il) * Nn + j0 + j];
    }
    // W1lo, interleaved-with-zero, pre-arranged per (s',t2,qd,nl) frag
    {
        unsigned int* p = (unsigned int*)sW1loD;
        for (int idx = tid; idx < 4096; idx += 256) {
            int pr = idx & 3, n = (idx >> 2) & 15, q4 = (idx >> 6) & 3;
            int t2 = (idx >> 8) & 3, sp = (idx >> 10) & 3;
            int k = sp * 16 + q4 * 4 + pr;
            float w = W1t[k * 64 + t2 * 16 + n];
            float whi = bf2f(f2bf(w));
            p[idx] = (unsigned int)f2bf(w - whi);    // low short = W1lo, high short = 0
        }
    }
    if (tid < 64) { sb1f[tid] = b1t[tid]; sw2f[tid] = W2t[tid]; }

    // ---------------- loop-invariant weight A-fragments ----------------
    short8 Aw0[3][4];                        // layer 1: A[m=hidden 16t+nl][k=feature]
    for (int s = 0; s < 3; ++s)
        for (int t = 0; t < 4; ++t) {
            short8 f;
            #pragma unroll
            for (int j = 0; j < 8; ++j) {
                int kg = s * 32 + qd * 8 + j;
                int col = t * 16 + nl;
                float v;
                if (kg < 80)       v = W0t[kg * 64 + col];
                else if (kg == 80) v = b0t[col];                    // bias feature (=1)
                else if (kg == 81) v = W0t[31 * 64 + col];          // qlo_1st x W31hi
                else if (kg == 82) v = W0t[63 * 64 + col];          // qlo_2nd x W63hi
                else if (kg == 83) { float w = W0t[31 * 64 + col]; v = w - bf2f(f2bf(w)); } // qhi_1st x W31lo
                else if (kg == 84) { float w = W0t[63 * 64 + col]; v = w - bf2f(f2bf(w)); } // qhi_2nd x W63lo
                else               v = 0.f;
                f[j] = (short)f2bf(v);
            }
            Aw0[s][t] = f;
        }
    short8 Aw1d[4][4];                       // layer 2 main: (W1hi,W1hi) dup over K'=128
    for (int sp = 0; sp < 4; ++sp)
        for (int t2 = 0; t2 < 4; ++t2) {
            short8 f;
            #pragma unroll
            for (int j = 0; j < 8; ++j) {
                int k = (sp * 32 + qd * 8 + j) >> 1;
                f[j] = (short)f2bf(W1t[k * 64 + t2 * 16 + nl]);
            }
            Aw1d[sp][t2] = f;
        }

    __syncthreads();

    const f32x4 z4 = {0.f, 0.f, 0.f, 0.f};

    // ---------------- 4 groups per wave: i = i0 + wv*4 + g ----------------
    for (int g = 0; g < 4; ++g) {
        const int il = wv * 4 + g;

        // layer-1 B-fragments: B[k=feature][n=pair]
        short8 Bai = *(const short8*)&sa[il][qd * 8];        // a_i (broadcast over pairs)
        short8 Baj = *(const short8*)&sa[16 + nl][qd * 8];   // a_j (per pair)
        short8 BeU, BeV;
        if (qd < 2) {
            short8 v = *(const short8*)&se[il][nl][qd * 8];  // e features 0..15
            BeU = v; BeV = v;
        } else if (qd == 2) {                                // kg 80..87
            short8 z = {0, 0, 0, 0, 0, 0, 0, 0};
            z[0] = (short)0x3F80;                            // 1.0 bf16 (bias feature)
            short qli = (short)sqres[il],      qlj = (short)sqres[16 + nl];
            short qhi = (short)sa[il][31],     qhj = (short)sa[16 + nl][31];
            BeU = z; BeU[1] = qli; BeU[2] = qlj; BeU[3] = qhi; BeU[4] = qhj;
            BeV = z; BeV[1] = qlj; BeV[2] = qli; BeV[3] = qhj; BeV[4] = qhi;
        } else {
            short8 z = {0, 0, 0, 0, 0, 0, 0, 0};
            BeU = z; BeV = z;
        }

        // layer 1: D1[hidden, pair], 24 MFMAs
        f32x4 aU[4], aV[4];
        #pragma unroll
        for (int t = 0; t < 4; ++t) {
            f32x4 x = MFMA16(Aw0[2][t], BeU, z4);
            x = MFMA16(Aw0[0][t], Bai, x);
            x = MFMA16(Aw0[1][t], Baj, x);
            aU[t] = x;
            f32x4 y = MFMA16(Aw0[2][t], BeV, z4);
            y = MFMA16(Aw0[0][t], Baj, y);
            y = MFMA16(Aw0[1][t], Bai, y);
            aV[t] = y;
        }

        // relu + hi/lo split, packed straight into layer-2 B-frags (no LDS!)
        short8 B2u[4], B2v[4];
        #pragma unroll
        for (int tp = 0; tp < 4; ++tp) {
            U8 pu, pv;
            #pragma unroll
            for (int r = 0; r < 4; ++r) {
                float u = fmaxf(aU[tp][r], 0.f);
                unsigned int ra = rne(u);
                float lo = u - __uint_as_float(ra & 0xFFFF0000u);
                pu.u[r] = (ra >> 16) | (rne(lo) & 0xFFFF0000u);   // (uhi, ulo)
                float v = fmaxf(aV[tp][r], 0.f);
                unsigned int rb = rne(v);
                float lov = v - __uint_as_float(rb & 0xFFFF0000u);
                pv.u[r] = (rb >> 16) | (rne(lov) & 0xFFFF0000u);
            }
            B2u[tp] = pu.s;
            B2v[tp] = pv.s;
        }

        // layer 2: 64 MFMAs (main dup-chain + W1lo correction chain)
        f32x4 hU[4], hV[4];
        #pragma unroll
        for (int t2 = 0; t2 < 4; ++t2) {
            f32x4 x = z4, y = z4;
            #pragma unroll
            for (int sp = 0; sp < 4; ++sp) {
                x = MFMA16(Aw1d[sp][t2], B2u[sp], x);
                y = MFMA16(Aw1d[sp][t2], B2v[sp], y);
            }
            #pragma unroll
            for (int sp = 0; sp < 4; ++sp) {
                short8 Ac = *(const short8*)&sW1loD[sp][t2][qd][nl][0];
                x = MFMA16(Ac, B2u[sp], x);
                y = MFMA16(Ac, B2v[sp], y);
            }
            hU[t2] = x; hV[t2] = y;
        }

        // layer 3 + antisym + mask + sums (h2 rows live at (t2, qd, r); pair = nl)
        float s = 0.f;
        #pragma unroll
        for (int t2 = 0; t2 < 4; ++t2) {
            float4 b1q = *(const float4*)&sb1f[t2 * 16 + qd * 4];
            float4 w2q = *(const float4*)&sw2f[t2 * 16 + qd * 4];
            s += (fmaxf(hU[t2][0] + b1q.x, 0.f) - fmaxf(hV[t2][0] + b1q.x, 0.f)) * w2q.x;
            s += (fmaxf(hU[t2][1] + b1q.y, 0.f) - fmaxf(hV[t2][1] + b1q.y, 0.f)) * w2q.y;
            s += (fmaxf(hU[t2][2] + b1q.z, 0.f) - fmaxf(hV[t2][2] + b1q.z, 0.f)) * w2q.z;
            s += (fmaxf(hU[t2][3] + b1q.w, 0.f) - fmaxf(hV[t2][3] + b1q.w, 0.f)) * w2q.w;
        }
        s += __shfl_xor(s, 16);          // combine the 4 quads -> full s for pair nl
        s += __shfl_xor(s, 32);
        s *= smask[il][nl];
        s += __shfl_xor(s, 1);           // sum the 16 pairs
        s += __shfl_xor(s, 2);
        s += __shfl_xor(s, 4);
        s += __shfl_xor(s, 8);
        if (lane == 0) atomicAdd(&qout[i0 + il], s);
    }
}

extern "C" void kernel_launch(void* const* d_in, const int* in_sizes, int n_in,
                              void* d_out, int out_size, void* d_ws, size_t ws_size,
                              hipStream_t stream) {
    const float* h    = (const float*)d_in[0];
    const float* e    = (const float*)d_in[1];
    const float* q    = (const float*)d_in[2];
    const float* mask = (const float*)d_in[3];
    const float* W0   = (const float*)d_in[5];
    const float* b0   = (const float*)d_in[6];
    const float* W1   = (const float*)d_in[7];
    const float* b1   = (const float*)d_in[8];
    const float* W2   = (const float*)d_in[9];
    // d_in[10] = b2 cancels in the antisymmetrization

    float* qout = (float*)d_out;
    float* qA   = (float*)d_ws;        // stable per-timestep snapshot of q

    hipMemcpyAsync(qout, q, Nn * sizeof(float), hipMemcpyDeviceToDevice, stream);
    for (int t = 0; t < 3; ++t) {
        hipMemcpyAsync(qA, qout, Nn * sizeof(float), hipMemcpyDeviceToDevice, stream);
        epn_mfma_kernel<<<dim3(64, 64), 256, 0, stream>>>(
            h, qA, e, mask,
            W0 + t * 80 * 64, b0 + t * 64,
            W1 + t * 64 * 64, b1 + t * 64,
            W2 + t * 64, qout);
    }
}

// Round 4
// 444.863 us; speedup vs baseline: 3.0897x; 2.1634x over previous
//
#include <hip/hip_runtime.h>

// EPN_flax, round 4: per timestep t,
//   prologue A (once): weight fragments (fp16, k-permuted) -> d_ws
//   prologue B (per t): P[atom][64] = a@W0[:32]+b0, Q[atom][64] = a@W0[32:64]  (fp32, x1/16)
//   main: per pair-tile, E = (e/1)@(W0e/16) via 4 f16 MFMAs;
//         u_s = relu(E + P_i + Q_j), v_s = relu(E + P_j + Q_i)   (all pre-scaled 1/16, fp32 adds)
//         h2/16 = u_s @ W1 via 16 f16 MFMAs (k-permuted frags -> register-only handoff)
//         s = sum_j mask * ( relu(16*h2u+b1) - relu(16*h2v+b1) ) . W2 ; atomicAdd into q_i
// b2 cancels in the antisymmetrization. P/Q fp32-exact => only e and activations are fp16.

constexpr int Nn = 1024;

typedef _Float16 half8 __attribute__((ext_vector_type(8)));
typedef __attribute__((ext_vector_type(4))) float f32x4;

#define MFMAH(A, B, C) __builtin_amdgcn_mfma_f32_16x16x32_f16(A, B, C, 0, 0, 0)

// ---------------- setup kernel: weight fragments (all 3 timesteps) ----------------
__global__ void epn_frag_kernel(const float* __restrict__ W0,   // [3][80][64]
                                const float* __restrict__ W1,   // [3][64][64]
                                half8* __restrict__ fw0e,       // [3][4][64]
                                half8* __restrict__ fw1)        // [3][2][4][64]
{
    const int tid = threadIdx.x;
    for (int idx = tid; idx < 3 * 4 * 64; idx += 256) {
        int lane = idx & 63, t = (idx >> 6) & 3, ts = idx >> 8;
        int nl = lane & 15, qd = lane >> 4;
        half8 f;
        #pragma unroll
        for (int j = 0; j < 8; ++j) {
            int k = qd * 8 + j;
            float v = (k < 16) ? W0[ts * 80 * 64 + (64 + k) * 64 + t * 16 + nl] * 0.0625f : 0.f;
            f[j] = (_Float16)v;
        }
        fw0e[idx] = f;
    }
    for (int idx = tid; idx < 3 * 2 * 4 * 64; idx += 256) {
        int lane = idx & 63, t2 = (idx >> 6) & 3, sp = (idx >> 8) & 1, ts = idx >> 9;
        int nl = lane & 15, qd = lane >> 4;
        half8 f;
        #pragma unroll
        for (int j = 0; j < 8; ++j) {
            int k = (2 * (j >> 2) + sp) * 16 + qd * 4 + (j & 3);   // sigma-permuted k
            f[j] = (_Float16)W1[ts * 64 * 64 + k * 64 + t2 * 16 + nl];
        }
        fw1[idx] = f;
    }
}

// ---------------- per-timestep projection: P,Q (fp32, pre-scaled 1/16) ----------------
__global__ __launch_bounds__(256) void epn_proj_kernel(
    const float* __restrict__ h, const float* __restrict__ qcur,
    const float* __restrict__ W0, const float* __restrict__ b0,
    float* __restrict__ P, float* __restrict__ Q)
{
    __shared__ float sa[4][32];
    const int tid = threadIdx.x;
    const int base = blockIdx.x * 4;
    if (tid < 128) {
        int la = tid >> 5, c = tid & 31, atom = base + la;
        sa[la][c] = (c < 31) ? h[atom * 31 + c] : qcur[atom];
    }
    __syncthreads();
    const int la = tid >> 6, m = tid & 63, atom = base + la;
    float accP = b0[m], accQ = 0.f;
    #pragma unroll
    for (int c = 0; c < 32; ++c) {
        float av = sa[la][c];
        accP = fmaf(av, W0[c * 64 + m], accP);
        accQ = fmaf(av, W0[(32 + c) * 64 + m], accQ);
    }
    P[atom * 64 + m] = accP * 0.0625f;
    Q[atom * 64 + m] = accQ * 0.0625f;
}

// ---------------- main pair kernel ----------------
__global__ __launch_bounds__(256) void epn_main_kernel(
    const float* __restrict__ e, const float* __restrict__ mask,
    const float* __restrict__ Pg, const float* __restrict__ Qg,
    const half8* __restrict__ fragW0e,   // [4][64]
    const half8* __restrict__ fragW1,    // [2][4][64]
    const float* __restrict__ b1t, const float* __restrict__ W2t,
    float* __restrict__ qout)
{
    __shared__ float sP[32][68];   // rows 0-15: i-atoms, 16-31: j-atoms (stride 68: free banks)
    __shared__ float sQ[32][68];

    const int tid  = threadIdx.x;
    const int lane = tid & 63;
    const int wv   = tid >> 6;
    const int nl   = lane & 15;
    const int qd   = lane >> 4;
    const int i0   = blockIdx.y * 16;
    const int j0   = blockIdx.x * 16;

    // stage P/Q (coalesced b128 global -> LDS)
    for (int idx = tid; idx < 512; idx += 256) {
        int r = idx >> 4, c4 = (idx & 15) * 4;
        int atom = (r < 16) ? (i0 + r) : (j0 + r - 16);
        *(float4*)&sP[r][c4] = *(const float4*)&Pg[atom * 64 + c4];
        *(float4*)&sQ[r][c4] = *(const float4*)&Qg[atom * 64 + c4];
    }

    // loop-invariant weight fragments (12 coalesced b128 loads)
    half8 Aw0e[4], Aw1[2][4];
    #pragma unroll
    for (int t = 0; t < 4; ++t) Aw0e[t] = fragW0e[t * 64 + lane];
    #pragma unroll
    for (int sp = 0; sp < 2; ++sp)
        #pragma unroll
        for (int t2 = 0; t2 < 4; ++t2) Aw1[sp][t2] = fragW1[(sp * 4 + t2) * 64 + lane];
    float4 b1q[4], w2q[4];
    #pragma unroll
    for (int t2 = 0; t2 < 4; ++t2) {
        b1q[t2] = *(const float4*)&b1t[t2 * 16 + qd * 4];
        w2q[t2] = *(const float4*)&W2t[t2 * 16 + qd * 4];
    }

    const bool act = (qd < 2);   // lanes holding real e-features (k<16)
    // prefetch group 0 e + all masks
    float4 eA, eB;
    if (act) {
        const float* ep = e + ((size_t)(i0 + wv * 4) * Nn + (j0 + nl)) * 16 + qd * 8;
        eA = *(const float4*)ep; eB = *(const float4*)(ep + 4);
    }
    float mv[4];
    #pragma unroll
    for (int g = 0; g < 4; ++g)
        mv[g] = mask[(size_t)(i0 + wv * 4 + g) * Nn + j0 + nl];

    __syncthreads();

    const f32x4 z4 = {0.f, 0.f, 0.f, 0.f};

    #pragma unroll
    for (int g = 0; g < 4; ++g) {
        const int il = wv * 4 + g;
        float4 ecA = eA, ecB = eB;
        if (g < 3 && act) {   // software prefetch next group's e
            const float* ep = e + ((size_t)(i0 + il + 1) * Nn + (j0 + nl)) * 16 + qd * 8;
            eA = *(const float4*)ep; eB = *(const float4*)(ep + 4);
        }
        half8 Be = {};
        if (act) {
            Be[0] = (_Float16)ecA.x; Be[1] = (_Float16)ecA.y;
            Be[2] = (_Float16)ecA.z; Be[3] = (_Float16)ecA.w;
            Be[4] = (_Float16)ecB.x; Be[5] = (_Float16)ecB.y;
            Be[6] = (_Float16)ecB.z; Be[7] = (_Float16)ecB.w;
        }

        // layer 1 E-term: 4 MFMAs, shared by both directions
        f32x4 Eacc[4];
        #pragma unroll
        for (int t = 0; t < 4; ++t) Eacc[t] = MFMAH(Aw0e[t], Be, z4);

        // u/v construct (fp32 adds) + fp16 pack straight into layer-2 B-frags
        half8 B2u[2], B2v[2];
        #pragma unroll
        for (int t = 0; t < 4; ++t) {
            float4 Pi = *(const float4*)&sP[il][t * 16 + qd * 4];
            float4 Qj = *(const float4*)&sQ[16 + nl][t * 16 + qd * 4];
            float4 Pj = *(const float4*)&sP[16 + nl][t * 16 + qd * 4];
            float4 Qi = *(const float4*)&sQ[il][t * 16 + qd * 4];
            const int sp = t & 1, hi = (t >> 1) * 4;
            #pragma unroll
            for (int r = 0; r < 4; ++r) {
                float pir = (r == 0 ? Pi.x : r == 1 ? Pi.y : r == 2 ? Pi.z : Pi.w);
                float qjr = (r == 0 ? Qj.x : r == 1 ? Qj.y : r == 2 ? Qj.z : Qj.w);
                float pjr = (r == 0 ? Pj.x : r == 1 ? Pj.y : r == 2 ? Pj.z : Pj.w);
                float qir = (r == 0 ? Qi.x : r == 1 ? Qi.y : r == 2 ? Qi.z : Qi.w);
                float uu = fmaxf(Eacc[t][r] + pir + qjr, 0.f);
                float vv = fmaxf(Eacc[t][r] + pjr + qir, 0.f);
                B2u[sp][hi + r] = (_Float16)uu;
                B2v[sp][hi + r] = (_Float16)vv;
            }
        }

        // layer 2: 16 MFMAs
        f32x4 hU[4], hV[4];
        #pragma unroll
        for (int t2 = 0; t2 < 4; ++t2) {
            f32x4 x = MFMAH(Aw1[0][t2], B2u[0], z4);
            hU[t2] = MFMAH(Aw1[1][t2], B2u[1], x);
            f32x4 y = MFMAH(Aw1[0][t2], B2v[0], z4);
            hV[t2] = MFMAH(Aw1[1][t2], B2v[1], y);
        }

        // layer 3 + antisym + mask + row-sum
        float s = 0.f;
        #pragma unroll
        for (int t2 = 0; t2 < 4; ++t2) {
            #pragma unroll
            for (int r = 0; r < 4; ++r) {
                float bb = (r == 0 ? b1q[t2].x : r == 1 ? b1q[t2].y : r == 2 ? b1q[t2].z : b1q[t2].w);
                float ww = (r == 0 ? w2q[t2].x : r == 1 ? w2q[t2].y : r == 2 ? w2q[t2].z : w2q[t2].w);
                float ru = fmaxf(fmaf(hU[t2][r], 16.f, bb), 0.f);
                float rv = fmaxf(fmaf(hV[t2][r], 16.f, bb), 0.f);
                s = fmaf(ru - rv, ww, s);
            }
        }
        s += __shfl_xor(s, 16);   // combine the 4 quads -> full s for pair nl
        s += __shfl_xor(s, 32);
        s *= mv[g];
        s += __shfl_xor(s, 1);    // sum the 16 pairs
        s += __shfl_xor(s, 2);
        s += __shfl_xor(s, 4);
        s += __shfl_xor(s, 8);
        if (lane == 0) atomicAdd(&qout[i0 + il], s);
    }
}

extern "C" void kernel_launch(void* const* d_in, const int* in_sizes, int n_in,
                              void* d_out, int out_size, void* d_ws, size_t ws_size,
                              hipStream_t stream) {
    const float* h    = (const float*)d_in[0];
    const float* e    = (const float*)d_in[1];
    const float* q    = (const float*)d_in[2];
    const float* mask = (const float*)d_in[3];
    const float* W0   = (const float*)d_in[5];
    const float* b0   = (const float*)d_in[6];
    const float* W1   = (const float*)d_in[7];
    const float* b1   = (const float*)d_in[8];
    const float* W2   = (const float*)d_in[9];
    // d_in[10] = b2 cancels in the antisymmetrization

    float* qout = (float*)d_out;
    char*  ws   = (char*)d_ws;
    float* Pws  = (float*)(ws);                       // 1024*64 f32 = 256 KB
    float* Qws  = (float*)(ws + 256 * 1024);          // 256 KB
    half8* fw0e = (half8*)(ws + 512 * 1024);          // 3*4*64*16 B = 12 KB
    half8* fw1  = (half8*)(ws + 512 * 1024 + 12288);  // 3*8*64*16 B = 24 KB

    hipMemcpyAsync(qout, q, Nn * sizeof(float), hipMemcpyDeviceToDevice, stream);
    epn_frag_kernel<<<1, 256, 0, stream>>>(W0, W1, fw0e, fw1);
    for (int t = 0; t < 3; ++t) {
        epn_proj_kernel<<<256, 256, 0, stream>>>(h, qout, W0 + t * 80 * 64, b0 + t * 64,
                                                 Pws, Qws);
        epn_main_kernel<<<dim3(64, 64), 256, 0, stream>>>(
            e, mask, Pws, Qws,
            fw0e + (size_t)t * 4 * 64, fw1 + (size_t)t * 8 * 64,
            b1 + t * 64, W2 + t * 64, qout);
    }
}

// Round 6
// 355.137 us; speedup vs baseline: 3.8704x; 1.2526x over previous
//
#include <hip/hip_runtime.h>

// EPN_flax, round 6 (= round-5 design, compile fix): P/Q fp32 per-atom
// projections; E-term + layer2 on f16 MFMA with k-permuted W1 fragments ->
// register-only layer1->layer2 handoff; 1/16 pre-scale; b2 cancels.
// Loop-invariant per-lane data (weight fragments, b1, W2) lives in LDS
// (frees ~80 VGPRs -> 4+ waves/SIMD via __launch_bounds__(256,4));
// activations packed with v_cvt_pkrtz_f16_f32; float2 math for pk-ops.

constexpr int Nn = 1024;

typedef _Float16 half8 __attribute__((ext_vector_type(8)));
typedef __fp16   fp16x2 __attribute__((ext_vector_type(2)));
typedef float    f32x4 __attribute__((ext_vector_type(4)));
typedef float    f32x2 __attribute__((ext_vector_type(2)));
typedef unsigned int uint4v __attribute__((ext_vector_type(4)));

#define MFMAH(A, B, C) __builtin_amdgcn_mfma_f32_16x16x32_f16(A, B, C, 0, 0, 0)

__device__ inline unsigned int pkrtz(float a, float b) {
    fp16x2 r = __builtin_amdgcn_cvt_pkrtz(a, b);
    return __builtin_bit_cast(unsigned int, r);
}
__device__ inline f32x2 max0(f32x2 a) {
    f32x2 z = {0.f, 0.f};
    return __builtin_elementwise_max(a, z);
}

// ---------------- setup kernel: weight fragments (all 3 timesteps) ----------------
__global__ void epn_frag_kernel(const float* __restrict__ W0,   // [3][80][64]
                                const float* __restrict__ W1,   // [3][64][64]
                                half8* __restrict__ fw0e,       // [3][4][64]
                                half8* __restrict__ fw1)        // [3][2][4][64]
{
    const int tid = threadIdx.x;
    for (int idx = tid; idx < 3 * 4 * 64; idx += 256) {
        int lane = idx & 63, t = (idx >> 6) & 3, ts = idx >> 8;
        int nl = lane & 15, qd = lane >> 4;
        half8 f;
        #pragma unroll
        for (int j = 0; j < 8; ++j) {
            int k = qd * 8 + j;
            float v = (k < 16) ? W0[ts * 80 * 64 + (64 + k) * 64 + t * 16 + nl] * 0.0625f : 0.f;
            f[j] = (_Float16)v;
        }
        fw0e[idx] = f;
    }
    for (int idx = tid; idx < 3 * 2 * 4 * 64; idx += 256) {
        int lane = idx & 63, t2 = (idx >> 6) & 3, sp = (idx >> 8) & 1, ts = idx >> 9;
        int nl = lane & 15, qd = lane >> 4;
        half8 f;
        #pragma unroll
        for (int j = 0; j < 8; ++j) {
            int k = (2 * (j >> 2) + sp) * 16 + qd * 4 + (j & 3);   // sigma-permuted k
            f[j] = (_Float16)W1[ts * 64 * 64 + k * 64 + t2 * 16 + nl];
        }
        fw1[(ts * 8 + sp * 4 + t2) * 64 + lane] = f;
    }
}

// ---------------- per-timestep projection: P,Q (fp32, pre-scaled 1/16) ----------------
__global__ __launch_bounds__(256) void epn_proj_kernel(
    const float* __restrict__ h, const float* __restrict__ qcur,
    const float* __restrict__ W0, const float* __restrict__ b0,
    float* __restrict__ P, float* __restrict__ Q)
{
    __shared__ float sa[4][32];
    const int tid = threadIdx.x;
    const int base = blockIdx.x * 4;
    if (tid < 128) {
        int la = tid >> 5, c = tid & 31, atom = base + la;
        sa[la][c] = (c < 31) ? h[atom * 31 + c] : qcur[atom];
    }
    __syncthreads();
    const int la = tid >> 6, m = tid & 63, atom = base + la;
    float accP = b0[m], accQ = 0.f;
    #pragma unroll
    for (int c = 0; c < 32; ++c) {
        float av = sa[la][c];
        accP = fmaf(av, W0[c * 64 + m], accP);
        accQ = fmaf(av, W0[(32 + c) * 64 + m], accQ);
    }
    P[atom * 64 + m] = accP * 0.0625f;
    Q[atom * 64 + m] = accQ * 0.0625f;
}

// ---------------- main pair kernel ----------------
__global__ __launch_bounds__(256, 4) void epn_main_kernel(
    const float* __restrict__ e, const float* __restrict__ mask,
    const float* __restrict__ Pg, const float* __restrict__ Qg,
    const half8* __restrict__ fragW0e,   // [4][64]
    const half8* __restrict__ fragW1,    // [8][64]  (sp*4+t2 major)
    const float* __restrict__ b1t, const float* __restrict__ W2t,
    float* __restrict__ qout)
{
    __shared__ float sP[32][68];           // rows 0-15: i-atoms, 16-31: j-atoms
    __shared__ float sQ[32][68];
    __shared__ __align__(16) uint4 sFragW[12][64];   // [0..3]=W0e frags, [4..11]=W1 frags
    __shared__ float sb1f[64];
    __shared__ float sw2f[64];

    const int tid  = threadIdx.x;
    const int lane = tid & 63;
    const int wv   = tid >> 6;
    const int nl   = lane & 15;
    const int qd   = lane >> 4;
    const int i0   = blockIdx.y * 16;
    const int j0   = blockIdx.x * 16;

    // stage P/Q (coalesced b128 global -> LDS)
    for (int idx = tid; idx < 512; idx += 256) {
        int r = idx >> 4, c4 = (idx & 15) * 4;
        int atom = (r < 16) ? (i0 + r) : (j0 + r - 16);
        *(float4*)&sP[r][c4] = *(const float4*)&Pg[atom * 64 + c4];
        *(float4*)&sQ[r][c4] = *(const float4*)&Qg[atom * 64 + c4];
    }
    // stage weight fragments (per-lane layout, 12 KB)
    {
        uint4* sf = (uint4*)sFragW;
        sf[tid] = ((const uint4*)fragW0e)[tid];
        for (int idx = tid; idx < 512; idx += 256)
            sf[256 + idx] = ((const uint4*)fragW1)[idx];
    }
    if (tid < 64) { sb1f[tid] = b1t[tid]; sw2f[tid] = W2t[tid]; }

    const bool act = (qd < 2);   // lanes holding real e-features (k<16)
    // prefetch group 0 e + mask
    float4 eA = {}, eB = {};
    if (act) {
        const float* ep = e + ((size_t)(i0 + wv * 4) * Nn + (j0 + nl)) * 16 + qd * 8;
        eA = *(const float4*)ep; eB = *(const float4*)(ep + 4);
    }
    float mvC = mask[(size_t)(i0 + wv * 4) * Nn + j0 + nl];

    __syncthreads();

    const f32x4 z4 = {0.f, 0.f, 0.f, 0.f};

    #pragma unroll
    for (int g = 0; g < 4; ++g) {
        const int il = wv * 4 + g;
        float4 ecA = eA, ecB = eB;
        float mcur = mvC;
        if (g < 3) {   // software prefetch next group's e + mask
            if (act) {
                const float* ep = e + ((size_t)(i0 + il + 1) * Nn + (j0 + nl)) * 16 + qd * 8;
                eA = *(const float4*)ep; eB = *(const float4*)(ep + 4);
            }
            mvC = mask[(size_t)(i0 + il + 1) * Nn + j0 + nl];
        }

        uint4v beu = {0u, 0u, 0u, 0u};
        if (act) {
            beu[0] = pkrtz(ecA.x, ecA.y); beu[1] = pkrtz(ecA.z, ecA.w);
            beu[2] = pkrtz(ecB.x, ecB.y); beu[3] = pkrtz(ecB.z, ecB.w);
        }
        const half8 Be = __builtin_bit_cast(half8, beu);

        // layer 1 E-term: 4 MFMAs (A-frags streamed from LDS)
        f32x4 Eacc[4];
        #pragma unroll
        for (int t = 0; t < 4; ++t) {
            half8 aw = *(const half8*)&sFragW[t][lane];
            Eacc[t] = MFMAH(aw, Be, z4);
        }

        // u/v construct (float2 pk math) -> pkrtz straight into layer-2 B-frags
        uint4v bu[2], bv[2];
        #pragma unroll
        for (int t = 0; t < 4; ++t) {
            f32x4 Pi4 = *(const f32x4*)&sP[il][t * 16 + qd * 4];        // broadcast
            f32x4 Qj4 = *(const f32x4*)&sQ[16 + nl][t * 16 + qd * 4];
            f32x4 Pj4 = *(const f32x4*)&sP[16 + nl][t * 16 + qd * 4];
            f32x4 Qi4 = *(const f32x4*)&sQ[il][t * 16 + qd * 4];
            const int sp = t & 1, base = (t >> 1) * 2;
            f32x2 E0 = {Eacc[t][0], Eacc[t][1]}, E1 = {Eacc[t][2], Eacc[t][3]};
            f32x2 pi0 = {Pi4[0], Pi4[1]}, pi1 = {Pi4[2], Pi4[3]};
            f32x2 qj0 = {Qj4[0], Qj4[1]}, qj1 = {Qj4[2], Qj4[3]};
            f32x2 pj0 = {Pj4[0], Pj4[1]}, pj1 = {Pj4[2], Pj4[3]};
            f32x2 qi0 = {Qi4[0], Qi4[1]}, qi1 = {Qi4[2], Qi4[3]};
            f32x2 u0 = max0(E0 + pi0 + qj0), u1 = max0(E1 + pi1 + qj1);
            f32x2 v0 = max0(E0 + pj0 + qi0), v1 = max0(E1 + pj1 + qi1);
            bu[sp][base + 0] = pkrtz(u0[0], u0[1]);
            bu[sp][base + 1] = pkrtz(u1[0], u1[1]);
            bv[sp][base + 0] = pkrtz(v0[0], v0[1]);
            bv[sp][base + 1] = pkrtz(v1[0], v1[1]);
        }
        const half8 B2u0 = __builtin_bit_cast(half8, bu[0]);
        const half8 B2u1 = __builtin_bit_cast(half8, bu[1]);
        const half8 B2v0 = __builtin_bit_cast(half8, bv[0]);
        const half8 B2v1 = __builtin_bit_cast(half8, bv[1]);

        // layer 2: 16 MFMAs (W1 frags streamed from LDS)
        f32x4 hU[4], hV[4];
        #pragma unroll
        for (int t2 = 0; t2 < 4; ++t2) {
            half8 w0 = *(const half8*)&sFragW[4 + t2][lane];
            half8 w1 = *(const half8*)&sFragW[8 + t2][lane];
            f32x4 x = MFMAH(w0, B2u0, z4);
            hU[t2] = MFMAH(w1, B2u1, x);
            f32x4 y = MFMAH(w0, B2v0, z4);
            hV[t2] = MFMAH(w1, B2v1, y);
        }

        // layer 3 + antisym + mask + row-sum (mask folded per-lane before reduce)
        f32x2 s2 = {0.f, 0.f};
        #pragma unroll
        for (int t2 = 0; t2 < 4; ++t2) {
            f32x4 b14 = *(const f32x4*)&sb1f[t2 * 16 + qd * 4];   // broadcast
            f32x4 w24 = *(const f32x4*)&sw2f[t2 * 16 + qd * 4];
            f32x2 hu0 = {hU[t2][0], hU[t2][1]}, hu1 = {hU[t2][2], hU[t2][3]};
            f32x2 hv0 = {hV[t2][0], hV[t2][1]}, hv1 = {hV[t2][2], hV[t2][3]};
            f32x2 b0v = {b14[0], b14[1]}, b1v = {b14[2], b14[3]};
            f32x2 w0v = {w24[0], w24[1]}, w1v = {w24[2], w24[3]};
            f32x2 ru0 = max0(hu0 * 16.f + b0v), ru1 = max0(hu1 * 16.f + b1v);
            f32x2 rv0 = max0(hv0 * 16.f + b0v), rv1 = max0(hv1 * 16.f + b1v);
            s2 += (ru0 - rv0) * w0v;
            s2 += (ru1 - rv1) * w1v;
        }
        float s = (s2[0] + s2[1]) * mcur;
        s += __shfl_xor(s, 1);
        s += __shfl_xor(s, 2);
        s += __shfl_xor(s, 4);
        s += __shfl_xor(s, 8);
        s += __shfl_xor(s, 16);
        s += __shfl_xor(s, 32);
        if (lane == 0) atomicAdd(&qout[i0 + il], s);
    }
}

extern "C" void kernel_launch(void* const* d_in, const int* in_sizes, int n_in,
                              void* d_out, int out_size, void* d_ws, size_t ws_size,
                              hipStream_t stream) {
    const float* h    = (const float*)d_in[0];
    const float* e    = (const float*)d_in[1];
    const float* q    = (const float*)d_in[2];
    const float* mask = (const float*)d_in[3];
    const float* W0   = (const float*)d_in[5];
    const float* b0   = (const float*)d_in[6];
    const float* W1   = (const float*)d_in[7];
    const float* b1   = (const float*)d_in[8];
    const float* W2   = (const float*)d_in[9];
    // d_in[10] = b2 cancels in the antisymmetrization

    float* qout = (float*)d_out;
    char*  ws   = (char*)d_ws;
    float* Pws  = (float*)(ws);                       // 256 KB
    float* Qws  = (float*)(ws + 256 * 1024);          // 256 KB
    half8* fw0e = (half8*)(ws + 512 * 1024);          // 12 KB
    half8* fw1  = (half8*)(ws + 512 * 1024 + 12288);  // 24 KB

    (void)hipMemcpyAsync(qout, q, Nn * sizeof(float), hipMemcpyDeviceToDevice, stream);
    epn_frag_kernel<<<1, 256, 0, stream>>>(W0, W1, fw0e, fw1);
    for (int t = 0; t < 3; ++t) {
        epn_proj_kernel<<<256, 256, 0, stream>>>(h, qout, W0 + t * 80 * 64, b0 + t * 64,
                                                 Pws, Qws);
        epn_main_kernel<<<dim3(64, 64), 256, 0, stream>>>(
            e, mask, Pws, Qws,
            fw0e + (size_t)t * 4 * 64, fw1 + (size_t)t * 8 * 64,
            b1 + t * 64, W2 + t * 64, qout);
    }
}

// Round 7
// 326.607 us; speedup vs baseline: 4.2084x; 1.0874x over previous
//
#include <hip/hip_runtime.h>

// EPN_flax, round 7: same algebra as rounds 4-6 (P/Q fp32 per-atom projections,
// E-term + layer2 on f16 MFMA with k-permuted W1 fragments -> register-only
// layer1->layer2 handoff, 1/16 pre-scale, b2 cancels).
// This round: (1) frag kernel parallelized (10 blocks) and absorbs the q->qout
// copy (one launch fewer, no serial 1-block prologue); (2) weight fragments
// held in REGISTERS (VGPR headroom measured at 44 in round 6) instead of LDS —
// cuts per-group LDS reads 36->24 and the associated address VALU.
// b1/W2 stay in LDS (cheap broadcast reads).

constexpr int Nn = 1024;

typedef _Float16 half8 __attribute__((ext_vector_type(8)));
typedef __fp16   fp16x2 __attribute__((ext_vector_type(2)));
typedef float    f32x4 __attribute__((ext_vector_type(4)));
typedef float    f32x2 __attribute__((ext_vector_type(2)));
typedef unsigned int uint4v __attribute__((ext_vector_type(4)));

#define MFMAH(A, B, C) __builtin_amdgcn_mfma_f32_16x16x32_f16(A, B, C, 0, 0, 0)

__device__ inline unsigned int pkrtz(float a, float b) {
    fp16x2 r = __builtin_amdgcn_cvt_pkrtz(a, b);
    return __builtin_bit_cast(unsigned int, r);
}
__device__ inline f32x2 max0(f32x2 a) {
    f32x2 z = {0.f, 0.f};
    return __builtin_elementwise_max(a, z);
}

// ---- setup kernel: weight fragments (all 3 timesteps) + q->qout copy ----
__global__ __launch_bounds__(256) void epn_frag_kernel(
    const float* __restrict__ W0,   // [3][80][64]
    const float* __restrict__ W1,   // [3][64][64]
    const float* __restrict__ qin,
    half8* __restrict__ fw0e,       // [3][4][64]
    half8* __restrict__ fw1,        // [3][8][64]
    float* __restrict__ qout)
{
    const int idx = blockIdx.x * 256 + threadIdx.x;   // grid = 10 blocks -> 2560
    if (idx < 768) {                                  // fw0e: (ts, t, lane)
        int lane = idx & 63, t = (idx >> 6) & 3, ts = idx >> 8;
        int nl = lane & 15, qd = lane >> 4;
        half8 f;
        #pragma unroll
        for (int j = 0; j < 8; ++j) {
            int k = qd * 8 + j;
            float v = (k < 16) ? W0[ts * 80 * 64 + (64 + k) * 64 + t * 16 + nl] * 0.0625f : 0.f;
            f[j] = (_Float16)v;
        }
        fw0e[idx] = f;
    } else if (idx < 2304) {                          // fw1: (ts, sp, t2, lane)
        int i2 = idx - 768;
        int lane = i2 & 63, t2 = (i2 >> 6) & 3, sp = (i2 >> 8) & 1, ts = i2 >> 9;
        int nl = lane & 15, qd = lane >> 4;
        half8 f;
        #pragma unroll
        for (int j = 0; j < 8; ++j) {
            int k = (2 * (j >> 2) + sp) * 16 + qd * 4 + (j & 3);   // sigma-permuted k
            f[j] = (_Float16)W1[ts * 64 * 64 + k * 64 + t2 * 16 + nl];
        }
        fw1[(ts * 8 + sp * 4 + t2) * 64 + lane] = f;
    } else {                                          // q -> qout (float4 x 256)
        int i4 = idx - 2304;
        *(float4*)&qout[i4 * 4] = *(const float4*)&qin[i4 * 4];
    }
}

// ---------------- per-timestep projection: P,Q (fp32, pre-scaled 1/16) ----------------
__global__ __launch_bounds__(256) void epn_proj_kernel(
    const float* __restrict__ h, const float* __restrict__ qcur,
    const float* __restrict__ W0, const float* __restrict__ b0,
    float* __restrict__ P, float* __restrict__ Q)
{
    __shared__ float sa[4][32];
    const int tid = threadIdx.x;
    const int base = blockIdx.x * 4;
    if (tid < 128) {
        int la = tid >> 5, c = tid & 31, atom = base + la;
        sa[la][c] = (c < 31) ? h[atom * 31 + c] : qcur[atom];
    }
    __syncthreads();
    const int la = tid >> 6, m = tid & 63, atom = base + la;
    float accP = b0[m], accQ = 0.f;
    #pragma unroll
    for (int c = 0; c < 32; ++c) {
        float av = sa[la][c];
        accP = fmaf(av, W0[c * 64 + m], accP);
        accQ = fmaf(av, W0[(32 + c) * 64 + m], accQ);
    }
    P[atom * 64 + m] = accP * 0.0625f;
    Q[atom * 64 + m] = accQ * 0.0625f;
}

// ---------------- main pair kernel ----------------
__global__ __launch_bounds__(256, 4) void epn_main_kernel(
    const float* __restrict__ e, const float* __restrict__ mask,
    const float* __restrict__ Pg, const float* __restrict__ Qg,
    const half8* __restrict__ fragW0e,   // [4][64]
    const half8* __restrict__ fragW1,    // [8][64]  (sp*4+t2 major)
    const float* __restrict__ b1t, const float* __restrict__ W2t,
    float* __restrict__ qout)
{
    __shared__ float sP[32][68];           // rows 0-15: i-atoms, 16-31: j-atoms
    __shared__ float sQ[32][68];
    __shared__ float sb1f[64];
    __shared__ float sw2f[64];

    const int tid  = threadIdx.x;
    const int lane = tid & 63;
    const int wv   = tid >> 6;
    const int nl   = lane & 15;
    const int qd   = lane >> 4;
    const int i0   = blockIdx.y * 16;
    const int j0   = blockIdx.x * 16;

    // stage P/Q (coalesced b128 global -> LDS)
    for (int idx = tid; idx < 512; idx += 256) {
        int r = idx >> 4, c4 = (idx & 15) * 4;
        int atom = (r < 16) ? (i0 + r) : (j0 + r - 16);
        *(float4*)&sP[r][c4] = *(const float4*)&Pg[atom * 64 + c4];
        *(float4*)&sQ[r][c4] = *(const float4*)&Qg[atom * 64 + c4];
    }
    if (tid < 64) { sb1f[tid] = b1t[tid]; sw2f[tid] = W2t[tid]; }

    // loop-invariant weight fragments in registers (12 coalesced b128 loads)
    half8 Aw0e[4], Aw1[8];
    #pragma unroll
    for (int t = 0; t < 4; ++t) Aw0e[t] = fragW0e[t * 64 + lane];
    #pragma unroll
    for (int i = 0; i < 8; ++i) Aw1[i] = fragW1[i * 64 + lane];

    const bool act = (qd < 2);   // lanes holding real e-features (k<16)
    // prefetch group 0 e + mask
    float4 eA = {}, eB = {};
    if (act) {
        const float* ep = e + ((size_t)(i0 + wv * 4) * Nn + (j0 + nl)) * 16 + qd * 8;
        eA = *(const float4*)ep; eB = *(const float4*)(ep + 4);
    }
    float mvC = mask[(size_t)(i0 + wv * 4) * Nn + j0 + nl];

    __syncthreads();

    const f32x4 z4 = {0.f, 0.f, 0.f, 0.f};

    #pragma unroll
    for (int g = 0; g < 4; ++g) {
        const int il = wv * 4 + g;
        float4 ecA = eA, ecB = eB;
        float mcur = mvC;
        if (g < 3) {   // software prefetch next group's e + mask
            if (act) {
                const float* ep = e + ((size_t)(i0 + il + 1) * Nn + (j0 + nl)) * 16 + qd * 8;
                eA = *(const float4*)ep; eB = *(const float4*)(ep + 4);
            }
            mvC = mask[(size_t)(i0 + il + 1) * Nn + j0 + nl];
        }

        uint4v beu = {0u, 0u, 0u, 0u};
        if (act) {
            beu[0] = pkrtz(ecA.x, ecA.y); beu[1] = pkrtz(ecA.z, ecA.w);
            beu[2] = pkrtz(ecB.x, ecB.y); beu[3] = pkrtz(ecB.z, ecB.w);
        }
        const half8 Be = __builtin_bit_cast(half8, beu);

        // layer 1 E-term: 4 MFMAs (register A-frags)
        f32x4 Eacc[4];
        #pragma unroll
        for (int t = 0; t < 4; ++t) Eacc[t] = MFMAH(Aw0e[t], Be, z4);

        // u/v construct (float2 pk math) -> pkrtz straight into layer-2 B-frags
        uint4v bu[2], bv[2];
        #pragma unroll
        for (int t = 0; t < 4; ++t) {
            f32x4 Pi4 = *(const f32x4*)&sP[il][t * 16 + qd * 4];        // broadcast
            f32x4 Qj4 = *(const f32x4*)&sQ[16 + nl][t * 16 + qd * 4];
            f32x4 Pj4 = *(const f32x4*)&sP[16 + nl][t * 16 + qd * 4];
            f32x4 Qi4 = *(const f32x4*)&sQ[il][t * 16 + qd * 4];
            const int sp = t & 1, base = (t >> 1) * 2;
            f32x2 E0 = {Eacc[t][0], Eacc[t][1]}, E1 = {Eacc[t][2], Eacc[t][3]};
            f32x2 pi0 = {Pi4[0], Pi4[1]}, pi1 = {Pi4[2], Pi4[3]};
            f32x2 qj0 = {Qj4[0], Qj4[1]}, qj1 = {Qj4[2], Qj4[3]};
            f32x2 pj0 = {Pj4[0], Pj4[1]}, pj1 = {Pj4[2], Pj4[3]};
            f32x2 qi0 = {Qi4[0], Qi4[1]}, qi1 = {Qi4[2], Qi4[3]};
            f32x2 u0 = max0(E0 + pi0 + qj0), u1 = max0(E1 + pi1 + qj1);
            f32x2 v0 = max0(E0 + pj0 + qi0), v1 = max0(E1 + pj1 + qi1);
            bu[sp][base + 0] = pkrtz(u0[0], u0[1]);
            bu[sp][base + 1] = pkrtz(u1[0], u1[1]);
            bv[sp][base + 0] = pkrtz(v0[0], v0[1]);
            bv[sp][base + 1] = pkrtz(v1[0], v1[1]);
        }
        const half8 B2u0 = __builtin_bit_cast(half8, bu[0]);
        const half8 B2u1 = __builtin_bit_cast(half8, bu[1]);
        const half8 B2v0 = __builtin_bit_cast(half8, bv[0]);
        const half8 B2v1 = __builtin_bit_cast(half8, bv[1]);

        // layer 2: 16 MFMAs (register A-frags)
        f32x4 hU[4], hV[4];
        #pragma unroll
        for (int t2 = 0; t2 < 4; ++t2) {
            f32x4 x = MFMAH(Aw1[t2], B2u0, z4);
            hU[t2] = MFMAH(Aw1[4 + t2], B2u1, x);
            f32x4 y = MFMAH(Aw1[t2], B2v0, z4);
            hV[t2] = MFMAH(Aw1[4 + t2], B2v1, y);
        }

        // layer 3 + antisym + mask + row-sum (mask folded per-lane before reduce)
        f32x2 s2 = {0.f, 0.f};
        #pragma unroll
        for (int t2 = 0; t2 < 4; ++t2) {
            f32x4 b14 = *(const f32x4*)&sb1f[t2 * 16 + qd * 4];   // broadcast
            f32x4 w24 = *(const f32x4*)&sw2f[t2 * 16 + qd * 4];
            f32x2 hu0 = {hU[t2][0], hU[t2][1]}, hu1 = {hU[t2][2], hU[t2][3]};
            f32x2 hv0 = {hV[t2][0], hV[t2][1]}, hv1 = {hV[t2][2], hV[t2][3]};
            f32x2 b0v = {b14[0], b14[1]}, b1v = {b14[2], b14[3]};
            f32x2 w0v = {w24[0], w24[1]}, w1v = {w24[2], w24[3]};
            f32x2 ru0 = max0(hu0 * 16.f + b0v), ru1 = max0(hu1 * 16.f + b1v);
            f32x2 rv0 = max0(hv0 * 16.f + b0v), rv1 = max0(hv1 * 16.f + b1v);
            s2 += (ru0 - rv0) * w0v;
            s2 += (ru1 - rv1) * w1v;
        }
        float s = (s2[0] + s2[1]) * mcur;
        s += __shfl_xor(s, 1);
        s += __shfl_xor(s, 2);
        s += __shfl_xor(s, 4);
        s += __shfl_xor(s, 8);
        s += __shfl_xor(s, 16);
        s += __shfl_xor(s, 32);
        if (lane == 0) atomicAdd(&qout[i0 + il], s);
    }
}

extern "C" void kernel_launch(void* const* d_in, const int* in_sizes, int n_in,
                              void* d_out, int out_size, void* d_ws, size_t ws_size,
                              hipStream_t stream) {
    const float* h    = (const float*)d_in[0];
    const float* e    = (const float*)d_in[1];
    const float* q    = (const float*)d_in[2];
    const float* mask = (const float*)d_in[3];
    const float* W0   = (const float*)d_in[5];
    const float* b0   = (const float*)d_in[6];
    const float* W1   = (const float*)d_in[7];
    const float* b1   = (const float*)d_in[8];
    const float* W2   = (const float*)d_in[9];
    // d_in[10] = b2 cancels in the antisymmetrization

    float* qout = (float*)d_out;
    char*  ws   = (char*)d_ws;
    float* Pws  = (float*)(ws);                       // 256 KB
    float* Qws  = (float*)(ws + 256 * 1024);          // 256 KB
    half8* fw0e = (half8*)(ws + 512 * 1024);          // 12 KB
    half8* fw1  = (half8*)(ws + 512 * 1024 + 12288);  // 24 KB

    epn_frag_kernel<<<10, 256, 0, stream>>>(W0, W1, q, fw0e, fw1, qout);
    for (int t = 0; t < 3; ++t) {
        epn_proj_kernel<<<256, 256, 0, stream>>>(h, qout, W0 + t * 80 * 64, b0 + t * 64,
                                                 Pws, Qws);
        epn_main_kernel<<<dim3(64, 64), 256, 0, stream>>>(
            e, mask, Pws, Qws,
            fw0e + (size_t)t * 4 * 64, fw1 + (size_t)t * 8 * 64,
            b1 + t * 64, W2 + t * 64, qout);
    }
}